// Round 11
// baseline (3773.241 us; speedup 1.0000x reference)
//
#include <hip/hip_runtime.h>

#define DD 128
#define K2 256      // concatenated K: [msg | ego*msg]
#define NBMAX 2048  // max bucket count (N/64)
#define COLMASK 0x01FFFFFF
#define LROW 132    // LDS msg row stride in floats (bank-spread)

typedef short short8 __attribute__((ext_vector_type(8)));
typedef float f32x4  __attribute__((ext_vector_type(4)));

static inline size_t align256(size_t x){ return (x + 255) & ~(size_t)255; }

__device__ __forceinline__ unsigned short f2bf(float x){
  unsigned int u = __builtin_bit_cast(unsigned int, x);
  u += 0x7fff + ((u >> 16) & 1);          // RNE fp32 -> bf16
  return (unsigned short)(u >> 16);
}
__device__ __forceinline__ float bf2f(unsigned short h){
  unsigned int u = ((unsigned int)h) << 16;
  return __builtin_bit_cast(float, u);
}

__device__ __forceinline__ short8 prod8(short8 mv, short8 ev){
  short8 r;
#pragma unroll
  for (int u = 0; u < 8; u++){
    float p = bf2f((unsigned short)mv[u]) * bf2f((unsigned short)ev[u]);
    r[u] = (short)f2bf(p);
  }
  return r;
}

// ---------------- bucket histogram (64-row buckets): LDS hist -> few global atomics --------
__global__ __launch_bounds__(256) void bucket_hist_kernel(
    const int* __restrict__ ei, int E, int* __restrict__ bcnt, int NB){
  __shared__ int lh[NBMAX];
  int t = threadIdx.x;
  int base = blockIdx.x * 8192;
  for (int j = t; j < NB; j += 256) lh[j] = 0;
  __syncthreads();
#pragma unroll
  for (int i = 0; i < 32; i++){
    int e = base + i*256 + t;
    if (e < E) atomicAdd(&lh[ei[e] >> 6], 1);
  }
  __syncthreads();
  for (int j = t; j < NB; j += 256){
    int c = lh[j];
    if (c) atomicAdd(&bcnt[j], c);
  }
}

// ---------------- bucket scan: bbase = excl scan(bcnt); bcur = bbase ----------------
__global__ __launch_bounds__(1024) void bucket_scan_kernel(
    const int* __restrict__ bcnt, int* __restrict__ bbase, int* __restrict__ bcur, int NB){
  __shared__ int a[NBMAX], btmp[NBMAX];
  int t = threadIdx.x;
  for (int i = t; i < NBMAX; i += 1024) a[i] = (i < NB) ? bcnt[i] : 0;
  __syncthreads();
  int* src = a; int* dst = btmp;
  for (int o = 1; o < NBMAX; o <<= 1){
    for (int i = t; i < NBMAX; i += 1024){
      int v = src[i];
      if (i >= o) v += src[i - o];
      dst[i] = v;
    }
    __syncthreads();
    int* tm = src; src = dst; dst = tm;
  }
  for (int i = t; i < NBMAX; i += 1024){
    if (i < NB){
      int excl = i ? src[i-1] : 0;
      bbase[i] = excl; bcur[i] = excl;
    }
  }
}

// ---------------- binned fill: append (rowlocal<<25 | col, w) into raw bucket regions ------
__global__ __launch_bounds__(256) void fill_binned_kernel(
    const int* __restrict__ ei, const float* __restrict__ ew, int E,
    int* __restrict__ bcur, int2* __restrict__ csre, int NB){
  __shared__ int lhist[NBMAX];
  __shared__ int lbase[NBMAX];
  int t = threadIdx.x;
  int base = blockIdx.x * 4096;
  for (int j = t; j < NB; j += 256) lhist[j] = 0;
  __syncthreads();
  int rows[16];
#pragma unroll
  for (int i = 0; i < 16; i++){
    int e = base + i*256 + t;
    int r = (e < E) ? ei[e] : -1;
    rows[i] = r;
    if (r >= 0) atomicAdd(&lhist[r >> 6], 1);
  }
  __syncthreads();
  for (int j = t; j < NB; j += 256){
    int c = lhist[j];
    lbase[j] = c ? atomicAdd(&bcur[j], c) : 0;
    lhist[j] = 0;
  }
  __syncthreads();
#pragma unroll
  for (int i = 0; i < 16; i++){
    int e = base + i*256 + t;
    int r = rows[i];
    if (r >= 0){
      int b = r >> 6;
      int pos = lbase[b] + atomicAdd(&lhist[b], 1);
      int col = ei[E + e];
      float w = ew[e];
      csre[pos] = make_int2(((r & 63) << 25) | col, __float_as_int(w));
    }
  }
}

// ---------------- fused: weight pack + emb->bf16 stage0 (interleaved feat4) ----------------
__global__ void pack_cvt_kernel(const float* __restrict__ gcw, const float* __restrict__ biw,
                                unsigned short* __restrict__ wb, int LYR,
                                const float* __restrict__ emb, unsigned int* __restrict__ feat4u,
                                int n2, int fsU){
  int i = blockIdx.x*blockDim.x + threadIdx.x;
  int wtotal = LYR*DD*K2;
  if (i < wtotal){
    int l = i / (DD*K2);
    int r = i - l*(DD*K2);
    int n = r >> 8;
    int k = r & (K2-1);
    float v = (k < DD) ? gcw[(size_t)l*DD*DD + n*DD + k]
                       : biw[(size_t)l*DD*DD + n*DD + (k - DD)];
    wb[i] = f2bf(v);
    return;
  }
  int j = i - wtotal;
  if (j < n2){
    float2 v = *(const float2*)(emb + (size_t)j*2);
    int n = j >> 6, c = j & 63;
    feat4u[(size_t)n*fsU + c] = (unsigned int)f2bf(v.x) | ((unsigned int)f2bf(v.y) << 16);
  }
}

// ---------------- fused layer: bucket gather (LDS fp32 accumulate) + MFMA transform --------
// One block per 64-row bucket. Phase 1: 4 waves stride the bucket's raw edge list in
// batches of 8 (no padding, no row boundaries), accumulating msg into LDS via ds_add_f32.
// Split column layout (even cols 0..63, odd 64..127) keeps LDS banks 2-way (free).
// Phase 2: K=256 bf16 MFMA transform (msg from LDS, ego from global), bias+leakyrelu+norm.
__global__ __launch_bounds__(256) void layer_bucket_kernel(
    const int* __restrict__ bbase, const int* __restrict__ bcur,
    const int2* __restrict__ csre,
    unsigned short* __restrict__ feat4, int fs, int loff, int ooff,
    const unsigned short* __restrict__ wb,
    const float* __restrict__ gcb, const float* __restrict__ bib,
    float* __restrict__ nscale, int N){
  __shared__ float lmsg[64*LROW];   // 33 KB
  int t = threadIdx.x;
  int wave = t >> 6, lane = t & 63;
  int b = blockIdx.x;
  int r0 = b*64;

  for (int i = t; i < 64*LROW; i += 256) lmsg[i] = 0.f;
  __syncthreads();

  // ---- phase 1: gather-accumulate ----
  int beg = bbase[b], bend = bcur[b];
  const unsigned short* fin = feat4 + loff;
  for (int k = beg + wave*8; k < bend; k += 32){
    int cnt = bend - k; cnt = cnt > 8 ? 8 : cnt;
    int2 e[8]; unsigned int v[8];
#pragma unroll
    for (int u = 0; u < 8; u++) e[u] = (u < cnt) ? csre[k+u] : make_int2(0,0);
#pragma unroll
    for (int u = 0; u < 8; u++)
      v[u] = *(const unsigned int*)(fin + (size_t)(e[u].x & COLMASK)*fs + lane*2);
#pragma unroll
    for (int u = 0; u < 8; u++){
      float w = __int_as_float(e[u].y);      // masked entries have w = 0 -> add 0
      int rl = ((unsigned int)e[u].x) >> 25;
      atomicAdd(&lmsg[rl*LROW + lane],      w * bf2f((unsigned short)v[u]));
      atomicAdd(&lmsg[rl*LROW + 64 + lane], w * bf2f((unsigned short)(v[u]>>16)));
    }
  }
  __syncthreads();

  // ---- phase 2: MFMA transform; wave handles rows wave*16 .. +15 ----
  int m = lane & 15, q = lane >> 4;
  int rl = wave*16 + m;
  int grow = r0 + rl;
  int crow = grow < N ? grow : N-1;
  const float* lrow = &lmsg[rl*LROW];
  const unsigned short* erow = feat4 + (size_t)crow*fs + loff;
  const unsigned short* wrow = wb + (size_t)m*K2;

  float bias[8];
#pragma unroll
  for (int ct = 0; ct < 8; ct++) bias[ct] = gcb[ct*16 + m] + bib[ct*16 + m];

  f32x4 acc[8];
#pragma unroll
  for (int ct = 0; ct < 8; ct++) acc[ct] = (f32x4)0.f;

#pragma unroll
  for (int kc = 0; kc < 4; kc++){
    int c = kc*32 + q*8;
    float4 ev = *(const float4*)&lrow[c >> 1];
    float4 od = *(const float4*)&lrow[64 + (c >> 1)];
    short8 mfrag;
    mfrag[0] = (short)f2bf(ev.x); mfrag[1] = (short)f2bf(od.x);
    mfrag[2] = (short)f2bf(ev.y); mfrag[3] = (short)f2bf(od.y);
    mfrag[4] = (short)f2bf(ev.z); mfrag[5] = (short)f2bf(od.z);
    mfrag[6] = (short)f2bf(ev.w); mfrag[7] = (short)f2bf(od.w);
    short8 efrag = *(const short8*)(erow + c);
    short8 pfrag = prod8(mfrag, efrag);
#pragma unroll
    for (int ct = 0; ct < 8; ct++){
      short8 bm = *(const short8*)(wrow + (size_t)ct*16*K2 + c);        // k < 128 half
      short8 bp = *(const short8*)(wrow + (size_t)ct*16*K2 + DD + c);   // k >= 128 half
      acc[ct] = __builtin_amdgcn_mfma_f32_16x16x32_bf16(mfrag, bm, acc[ct], 0, 0, 0);
      acc[ct] = __builtin_amdgcn_mfma_f32_16x16x32_bf16(pfrag, bp, acc[ct], 0, 0, 0);
    }
  }

  // epilogue: bias + leaky_relu + bf16 store + row-norm scale (row = r0 + wave*16 + q*4 + reg)
#pragma unroll
  for (int reg = 0; reg < 4; reg++){
    int gr = r0 + wave*16 + q*4 + reg;
    float rs = 0.f;
#pragma unroll
    for (int ct = 0; ct < 8; ct++){
      float x = acc[ct][reg] + bias[ct];
      x = (x > 0.f) ? x : 0.2f*x;
      rs += x*x;
      if (gr < N) feat4[(size_t)gr*fs + ooff + ct*16 + m] = f2bf(x);
    }
#pragma unroll
    for (int o = 1; o < 16; o <<= 1) rs += __shfl_xor(rs, o, 16);
    if (m == 0 && gr < N) nscale[gr] = 1.0f / fmaxf(sqrtf(rs), 1e-12f);
  }
}

// ---------------- score: single pass, interleaved 4-stage rows ----------------
__global__ void score_all_kernel(const int* __restrict__ eli, int Q,
                                 const unsigned int* __restrict__ feat4u, int fsU,
                                 const float* __restrict__ nsall, int N,
                                 float* __restrict__ out){
  int wid = (int)(((size_t)blockIdx.x*blockDim.x + threadIdx.x) >> 6);
  int lane = threadIdx.x & 63;
  if (wid >= Q) return;
  int s = eli[wid];
  int d = eli[Q + wid];
  const unsigned int* sr = feat4u + (size_t)s*fsU + lane;
  const unsigned int* dr = feat4u + (size_t)d*fsU + lane;
  unsigned int a0 = sr[0],   b0 = dr[0];
  unsigned int a1 = sr[64],  b1 = dr[64];
  unsigned int a2 = sr[128], b2 = dr[128];
  unsigned int a3 = sr[192], b3 = dr[192];
  float p0 = bf2f((unsigned short)a0)*bf2f((unsigned short)b0)
           + bf2f((unsigned short)(a0>>16))*bf2f((unsigned short)(b0>>16));
  float p1 = bf2f((unsigned short)a1)*bf2f((unsigned short)b1)
           + bf2f((unsigned short)(a1>>16))*bf2f((unsigned short)(b1>>16));
  float p2 = bf2f((unsigned short)a2)*bf2f((unsigned short)b2)
           + bf2f((unsigned short)(a2>>16))*bf2f((unsigned short)(b2>>16));
  float p3 = bf2f((unsigned short)a3)*bf2f((unsigned short)b3)
           + bf2f((unsigned short)(a3>>16))*bf2f((unsigned short)(b3>>16));
  for (int o = 32; o > 0; o >>= 1){
    p0 += __shfl_xor(p0, o, 64);
    p1 += __shfl_xor(p1, o, 64);
    p2 += __shfl_xor(p2, o, 64);
    p3 += __shfl_xor(p3, o, 64);
  }
  if (lane == 0){
    float r = p0;
    r += p1 * nsall[s]       * nsall[d];
    r += p2 * nsall[N + s]   * nsall[N + d];
    r += p3 * nsall[2*N + s] * nsall[2*N + d];
    out[wid] = r;
  }
}

extern "C" void kernel_launch(void* const* d_in, const int* in_sizes, int n_in,
                              void* d_out, int out_size, void* d_ws, size_t ws_size,
                              hipStream_t stream){
  const int*   edge_index = (const int*)d_in[0];
  const int*   eli        = (const int*)d_in[1];
  const float* ew         = (const float*)d_in[2];
  const float* emb        = (const float*)d_in[3];
  const float* gcw        = (const float*)d_in[4];
  const float* gcb        = (const float*)d_in[5];
  const float* biw        = (const float*)d_in[6];
  const float* bib        = (const float*)d_in[7];
  const int E   = in_sizes[2];
  const int Q   = in_sizes[1] / 2;
  const int N   = in_sizes[3] / DD;
  const int LYR = in_sizes[4] / (DD*DD);
  float* out = (float*)d_out;

  const int FS  = (LYR + 1) * DD;   // interleaved per-node feature stride (512 for LYR=3)
  const int FSU = FS / 2;

  char* base = (char*)d_ws;
  size_t off = 0;
  auto carve = [&](size_t bytes)->char*{
    char* r = base + off;
    off = align256(off + bytes);
    return r;
  };

  unsigned short* feat4  = (unsigned short*) carve((size_t)N*FS*sizeof(unsigned short));
  int2*           csre   = (int2*)           carve((size_t)E*sizeof(int2));
  unsigned short* wb     = (unsigned short*) carve((size_t)LYR*DD*K2*sizeof(unsigned short));
  float*          nsall  = (float*)          carve((size_t)3*N*sizeof(float));
  int*            bcnt   = (int*)            carve((size_t)NBMAX*sizeof(int));
  int*            bbase  = (int*)            carve((size_t)NBMAX*sizeof(int));
  int*            bcur   = (int*)            carve((size_t)NBMAX*sizeof(int));
  (void)n_in; (void)out_size; (void)ws_size;

  const int NB = (N + 63)/64;

  // setup: hist -> scan -> raw binned fill -> pack+cvt   (no CSR sort needed)
  hipMemsetAsync(bcnt, 0, (size_t)NB*sizeof(int), stream);
  bucket_hist_kernel<<<(E + 8191)/8192, 256, 0, stream>>>(edge_index, E, bcnt, NB);
  bucket_scan_kernel<<<1, 1024, 0, stream>>>(bcnt, bbase, bcur, NB);
  fill_binned_kernel<<<(E + 4095)/4096, 256, 0, stream>>>(edge_index, ew, E, bcur, csre, NB);
  {
    int total = LYR*DD*K2 + N*DD/2;
    pack_cvt_kernel<<<(total + 255)/256, 256, 0, stream>>>(
        gcw, biw, wb, LYR, emb, (unsigned int*)feat4, N*DD/2, FSU);
  }

  for (int l = 0; l < LYR; l++){
    layer_bucket_kernel<<<NB, 256, 0, stream>>>(
        bbase, bcur, csre, feat4, FS, l*DD, (l+1)*DD,
        wb + (size_t)l*DD*K2, gcb + (size_t)l*DD, bib + (size_t)l*DD,
        nsall + (size_t)l*N, N);
  }
  {
    int blocks = (int)(((size_t)Q*64 + 255)/256);
    score_all_kernel<<<blocks, 256, 0, stream>>>(eli, Q, (const unsigned int*)feat4, FSU,
                                                 nsall, N, out);
  }
}

// Round 12
// 548.866 us; speedup vs baseline: 6.8746x; 6.8746x over previous
//
#include <hip/hip_runtime.h>

#define DD 128
#define K2 256     // concatenated K: [msg | ego*msg]
#define NBMAX 1024 // max bucket count (N/128)
#define COLMASK 0x01FFFFFF
#define SCAP 4096  // sortbkt LDS out-buffer capacity (entries)

typedef short short8 __attribute__((ext_vector_type(8)));
typedef float f32x4  __attribute__((ext_vector_type(4)));

static inline size_t align256(size_t x){ return (x + 255) & ~(size_t)255; }

__device__ __forceinline__ unsigned short f2bf(float x){
  unsigned int u = __builtin_bit_cast(unsigned int, x);
  u += 0x7fff + ((u >> 16) & 1);          // RNE fp32 -> bf16
  return (unsigned short)(u >> 16);
}
__device__ __forceinline__ float bf2f(unsigned short h){
  unsigned int u = ((unsigned int)h) << 16;
  return __builtin_bit_cast(float, u);
}

__device__ __forceinline__ short8 prod8(short8 mv, short8 ev){
  short8 r;
#pragma unroll
  for (int u = 0; u < 8; u++){
    float p = bf2f((unsigned short)mv[u]) * bf2f((unsigned short)ev[u]);
    r[u] = (short)f2bf(p);
  }
  return r;
}

// ---------------- bucket histogram: LDS hist -> few global atomics ----------------
__global__ __launch_bounds__(256) void bucket_hist_kernel(
    const int* __restrict__ ei, int E, int* __restrict__ bcnt, int NB){
  __shared__ int lh[NBMAX];
  int t = threadIdx.x;
  int base = blockIdx.x * 8192;
  for (int j = t; j < NB; j += 256) lh[j] = 0;
  __syncthreads();
#pragma unroll
  for (int i = 0; i < 32; i++){
    int e = base + i*256 + t;
    if (e < E) atomicAdd(&lh[ei[e] >> 7], 1);
  }
  __syncthreads();
  for (int j = t; j < NB; j += 256){
    int c = lh[j];
    if (c) atomicAdd(&bcnt[j], c);
  }
}

// ---------------- bucket scan: bbase = excl scan(bcnt); bcur = bbase ----------------
__global__ __launch_bounds__(1024) void bucket_scan_kernel(
    const int* __restrict__ bcnt, int* __restrict__ bbase, int* __restrict__ bcur, int NB){
  __shared__ int a[NBMAX], btmp[NBMAX];
  int t = threadIdx.x;
  a[t] = (t < NB) ? bcnt[t] : 0;
  __syncthreads();
  int* src = a; int* dst = btmp;
  for (int o = 1; o < 1024; o <<= 1){
    int val = src[t];
    if (t >= o) val += src[t - o];
    dst[t] = val;
    __syncthreads();
    int* tm = src; src = dst; dst = tm;
  }
  int excl = (t == 0) ? 0 : src[t-1];
  if (t < NB){ bbase[t] = excl; bcur[t] = excl; }
}

// ---------------- binned fill, phase A ----------------
__global__ __launch_bounds__(256) void fill_binned_kernel(
    const int* __restrict__ ei, const float* __restrict__ ew, int E,
    int* __restrict__ bcur, int2* __restrict__ csre, int NB){
  __shared__ int lhist[NBMAX];
  __shared__ int lbase[NBMAX];
  int t = threadIdx.x;
  int base = blockIdx.x * 4096;
  for (int j = t; j < NB; j += 256) lhist[j] = 0;
  __syncthreads();
  int rows[16];
#pragma unroll
  for (int i = 0; i < 16; i++){
    int e = base + i*256 + t;
    int r = (e < E) ? ei[e] : -1;
    rows[i] = r;
    if (r >= 0) atomicAdd(&lhist[r >> 7], 1);
  }
  __syncthreads();
  for (int j = t; j < NB; j += 256){
    int c = lhist[j];
    lbase[j] = c ? atomicAdd(&bcur[j], c) : 0;
    lhist[j] = 0;
  }
  __syncthreads();
#pragma unroll
  for (int i = 0; i < 16; i++){
    int e = base + i*256 + t;
    int r = rows[i];
    if (r >= 0){
      int b = r >> 7;
      int pos = lbase[b] + atomicAdd(&lhist[b], 1);
      int col = ei[E + e];
      float w = ew[e];
      csre[pos] = make_int2(((r & 127) << 25) | col, __float_as_int(w));
    }
  }
}

// ---------------- per-bucket row degrees + padded bucket sums ----------------
__global__ __launch_bounds__(256) void bucket_rowdeg_kernel(
    const int* __restrict__ bbase, const int* __restrict__ bcur,
    const int2* __restrict__ csre, int* __restrict__ deg, int* __restrict__ psum, int N){
  __shared__ int lc[128];
  __shared__ int red[128];
  int b = blockIdx.x, t = threadIdx.x;
  if (t < 128) lc[t] = 0;
  __syncthreads();
  int beg = bbase[b], end = bcur[b];
  for (int i = beg + t; i < end; i += 256)
    atomicAdd(&lc[((unsigned int)csre[i].x) >> 25], 1);
  __syncthreads();
  int gr = b*128 + t;
  int d = 0;
  if (t < 128 && gr < N){ d = lc[t]; deg[gr] = d; }
  if (t < 128) red[t] = (d + 7) & ~7;
  __syncthreads();
  for (int o = 64; o > 0; o >>= 1){
    if (t < o) red[t] += red[t+o];
    __syncthreads();
  }
  if (t == 0) psum[b] = red[0];
}

// ---------------- padded-bucket scan ----------------
__global__ __launch_bounds__(1024) void pscan_kernel(
    const int* __restrict__ psum, int* __restrict__ pbase, int* __restrict__ rowptrN, int NB){
  __shared__ int a[NBMAX], btmp[NBMAX];
  int t = threadIdx.x;
  a[t] = (t < NB) ? psum[t] : 0;
  __syncthreads();
  int* src = a; int* dst = btmp;
  for (int o = 1; o < 1024; o <<= 1){
    int val = src[t];
    if (t >= o) val += src[t - o];
    dst[t] = val;
    __syncthreads();
    int* tm = src; src = dst; dst = tm;
  }
  int excl = (t == 0) ? 0 : src[t-1];
  if (t < NB) pbase[t] = excl;
  if (t == NB-1) *rowptrN = excl + psum[t];
}

// ---------------- phase B: local rowptr derivation + LDS-staged rank/pad -> coalesced ------
__global__ __launch_bounds__(256) void sortbkt_kernel(
    const int* __restrict__ pbase, const int* __restrict__ bbase, const int* __restrict__ bcur,
    const int* __restrict__ deg, const int2* __restrict__ csre, int2* __restrict__ csre2,
    int* __restrict__ rowptr, int N){
  __shared__ int2 obuf[SCAP];
  __shared__ int lrp[129];
  __shared__ int lcur[128];
  __shared__ int sa[128], sb[128];
  int b = blockIdx.x;
  int t = threadIdx.x;
  int r0 = b*128;
  int gr = r0 + t;
  int d = (t < 128 && gr < N) ? deg[gr] : 0;
  if (t < 128){ sa[t] = (d + 7) & ~7; lcur[t] = 0; }
  __syncthreads();
  int* s0 = sa; int* s1 = sb;
  for (int o = 1; o < 128; o <<= 1){
    if (t < 128){
      int v = s0[t];
      if (t >= o) v += s0[t - o];
      s1[t] = v;
    }
    __syncthreads();
    int* tm = s0; s0 = s1; s1 = tm;
  }
  int pb = pbase[b];
  if (t < 128){
    int excl = t ? s0[t-1] : 0;
    lrp[t] = pb + excl;
    if (gr < N) rowptr[gr] = pb + excl;
    if (t == 127) lrp[128] = pb + s0[127];
  }
  __syncthreads();

  int gb = lrp[0];
  int outLen = lrp[128] - gb;
  int beg = bbase[b], bend = bcur[b];

  if (outLen <= SCAP){
    for (int i = beg + t; i < bend; i += 256){
      int2 e = csre[i];
      int rl = ((unsigned int)e.x) >> 25;
      int pos = lrp[rl] - gb + atomicAdd(&lcur[rl], 1);
      obuf[pos] = e;
    }
    if (t < 128 && gr < N){
      int pbg = lrp[t] - gb + d, pe = lrp[t+1] - gb;
      int2 pad = make_int2(gr, 0);
      for (int i = pbg; i < pe; i++) obuf[i] = pad;
    }
    __syncthreads();
    for (int i = t; i < outLen; i += 256) csre2[gb + i] = obuf[i];
  } else {
    for (int i = beg + t; i < bend; i += 256){
      int2 e = csre[i];
      int rl = ((unsigned int)e.x) >> 25;
      int pos = lrp[rl] + atomicAdd(&lcur[rl], 1);
      csre2[pos] = e;
    }
    __syncthreads();
    if (t < 128 && gr < N){
      int pbeg = lrp[t] + lcur[t];
      int pend = lrp[t+1];
      int2 pad = make_int2(gr, 0);
      for (int i = pbeg; i < pend; i++) csre2[i] = pad;
    }
  }
}

// ---------------- fused: weight pack + emb->bf16 stage0 (interleaved feat4) ----------------
__global__ void pack_cvt_kernel(const float* __restrict__ gcw, const float* __restrict__ biw,
                                unsigned short* __restrict__ wb, int LYR,
                                const float* __restrict__ emb, unsigned int* __restrict__ feat4u,
                                int n2, int fsU){
  int i = blockIdx.x*blockDim.x + threadIdx.x;
  int wtotal = LYR*DD*K2;
  if (i < wtotal){
    int l = i / (DD*K2);
    int r = i - l*(DD*K2);
    int n = r >> 8;
    int k = r & (K2-1);
    float v = (k < DD) ? gcw[(size_t)l*DD*DD + n*DD + k]
                       : biw[(size_t)l*DD*DD + n*DD + (k - DD)];
    wb[i] = f2bf(v);
    return;
  }
  int j = i - wtotal;
  if (j < n2){
    float2 v = *(const float2*)(emb + (size_t)j*2);
    int n = j >> 6, c = j & 63;
    feat4u[(size_t)n*fsU + c] = (unsigned int)f2bf(v.x) | ((unsigned int)f2bf(v.y) << 16);
  }
}

// ---------------- gather (tail-free, rows padded x8): 16-deep MLP ----------------
__global__ void gather_kernel(const int* __restrict__ rowptr, const int2* __restrict__ csre,
                              const unsigned short* __restrict__ feat, int fs,
                              unsigned int* __restrict__ msgh, int N){
  int wid = (int)(((size_t)blockIdx.x*blockDim.x + threadIdx.x) >> 6);
  int lane = threadIdx.x & 63;
  if (wid >= N) return;
  int beg = rowptr[wid], end = rowptr[wid+1];
  float ax = 0.f, ay = 0.f;
  int k = beg;
  for (; k + 16 <= end; k += 16){     // 16 independent row-gathers in flight
    int2 e[16]; unsigned int v[16];
#pragma unroll
    for (int u = 0; u < 16; u++) e[u] = csre[k+u];
#pragma unroll
    for (int u = 0; u < 16; u++)
      v[u] = *(const unsigned int*)(feat + (size_t)(e[u].x & COLMASK)*fs + lane*2);
#pragma unroll
    for (int u = 0; u < 16; u++){
      float w = __int_as_float(e[u].y);
      ax = fmaf(w, bf2f((unsigned short)v[u]), ax);
      ay = fmaf(w, bf2f((unsigned short)(v[u]>>16)), ay);
    }
  }
  for (; k < end; k += 8){            // at most one trailing 8-batch (rows padded x8)
    int2 e[8]; unsigned int v[8];
#pragma unroll
    for (int u = 0; u < 8; u++) e[u] = csre[k+u];
#pragma unroll
    for (int u = 0; u < 8; u++)
      v[u] = *(const unsigned int*)(feat + (size_t)(e[u].x & COLMASK)*fs + lane*2);
#pragma unroll
    for (int u = 0; u < 8; u++){
      float w = __int_as_float(e[u].y);
      ax = fmaf(w, bf2f((unsigned short)v[u]), ax);
      ay = fmaf(w, bf2f((unsigned short)(v[u]>>16)), ay);
    }
  }
  msgh[(size_t)wid*(DD/2) + lane] = (unsigned int)f2bf(ax) | ((unsigned int)f2bf(ay) << 16);
}

// ---------------- transform (bf16 MFMA, K=256), LDS-free, strided feature rows ----------
__global__ __launch_bounds__(256) void transform_mfma_kernel(
    const unsigned short* __restrict__ ego_in, const unsigned short* __restrict__ msgh,
    int fs, const unsigned short* __restrict__ wb, const float* __restrict__ gcb,
    const float* __restrict__ bib, unsigned short* __restrict__ ego_out,
    float* __restrict__ nscale, int N){   // nscale: stride-3 base for this layer
  int t = threadIdx.x;
  int wave = t >> 6, lane = t & 63;
  int m = lane & 15, q = lane >> 4;
  int wr0 = blockIdx.x * 128 + wave * 32;

  float bias[8];
#pragma unroll
  for (int ct = 0; ct < 8; ct++) bias[ct] = gcb[ct*16 + m] + bib[ct*16 + m];

  int row0 = wr0 + m, row1 = wr0 + 16 + m;
  int cr0 = row0 < N ? row0 : N-1;
  int cr1 = row1 < N ? row1 : N-1;
  const unsigned short* mrow0 = msgh   + (size_t)cr0*DD;
  const unsigned short* mrow1 = msgh   + (size_t)cr1*DD;
  const unsigned short* erow0 = ego_in + (size_t)cr0*fs;
  const unsigned short* erow1 = ego_in + (size_t)cr1*fs;
  const unsigned short* wrow  = wb + (size_t)m*K2;

  f32x4 acc[8][2];
#pragma unroll
  for (int ct = 0; ct < 8; ct++){ acc[ct][0] = (f32x4)0.f; acc[ct][1] = (f32x4)0.f; }

#pragma unroll
  for (int cc = 0; cc < 4; cc++){
    int c = cc*32 + q*8;
    short8 m0 = *(const short8*)(mrow0 + c);
    short8 m1 = *(const short8*)(mrow1 + c);
    short8 e0 = *(const short8*)(erow0 + c);
    short8 e1 = *(const short8*)(erow1 + c);
    short8 p0 = prod8(m0, e0);
    short8 p1 = prod8(m1, e1);
#pragma unroll
    for (int ct = 0; ct < 8; ct++){
      short8 bm = *(const short8*)(wrow + (size_t)ct*16*K2 + c);
      short8 bp = *(const short8*)(wrow + (size_t)ct*16*K2 + DD + c);
      acc[ct][0] = __builtin_amdgcn_mfma_f32_16x16x32_bf16(m0, bm, acc[ct][0], 0, 0, 0);
      acc[ct][1] = __builtin_amdgcn_mfma_f32_16x16x32_bf16(m1, bm, acc[ct][1], 0, 0, 0);
      acc[ct][0] = __builtin_amdgcn_mfma_f32_16x16x32_bf16(p0, bp, acc[ct][0], 0, 0, 0);
      acc[ct][1] = __builtin_amdgcn_mfma_f32_16x16x32_bf16(p1, bp, acc[ct][1], 0, 0, 0);
    }
  }

#pragma unroll
  for (int rt = 0; rt < 2; rt++){
#pragma unroll
    for (int reg = 0; reg < 4; reg++){
      int gr = wr0 + rt*16 + q*4 + reg;
      float rs = 0.f;
#pragma unroll
      for (int ct = 0; ct < 8; ct++){
        float x = acc[ct][rt][reg] + bias[ct];
        x = (x > 0.f) ? x : 0.2f*x;
        rs += x*x;
        if (gr < N) ego_out[(size_t)gr*fs + ct*16 + m] = f2bf(x);
      }
#pragma unroll
      for (int o = 1; o < 16; o <<= 1) rs += __shfl_xor(rs, o, 16);
      if (m == 0 && gr < N)
        nscale[(size_t)gr*3] = 1.0f / fmaxf(sqrtf(rs), 1e-12f);
    }
  }
}

// ---------------- score: single pass, interleaved 4-stage rows + interleaved scales --------
__global__ void score_all_kernel(const int* __restrict__ eli, int Q,
                                 const unsigned int* __restrict__ feat4u, int fsU,
                                 const float* __restrict__ nsall,  // [n][3]
                                 float* __restrict__ out){
  int wid = (int)(((size_t)blockIdx.x*blockDim.x + threadIdx.x) >> 6);
  int lane = threadIdx.x & 63;
  if (wid >= Q) return;
  int s = eli[wid];
  int d = eli[Q + wid];
  const unsigned int* sr = feat4u + (size_t)s*fsU + lane;
  const unsigned int* dr = feat4u + (size_t)d*fsU + lane;
  unsigned int a0 = sr[0],   b0 = dr[0];
  unsigned int a1 = sr[64],  b1 = dr[64];
  unsigned int a2 = sr[128], b2 = dr[128];
  unsigned int a3 = sr[192], b3 = dr[192];
  float p0 = bf2f((unsigned short)a0)*bf2f((unsigned short)b0)
           + bf2f((unsigned short)(a0>>16))*bf2f((unsigned short)(b0>>16));
  float p1 = bf2f((unsigned short)a1)*bf2f((unsigned short)b1)
           + bf2f((unsigned short)(a1>>16))*bf2f((unsigned short)(b1>>16));
  float p2 = bf2f((unsigned short)a2)*bf2f((unsigned short)b2)
           + bf2f((unsigned short)(a2>>16))*bf2f((unsigned short)(b2>>16));
  float p3 = bf2f((unsigned short)a3)*bf2f((unsigned short)b3)
           + bf2f((unsigned short)(a3>>16))*bf2f((unsigned short)(b3>>16));
  for (int o = 32; o > 0; o >>= 1){
    p0 += __shfl_xor(p0, o, 64);
    p1 += __shfl_xor(p1, o, 64);
    p2 += __shfl_xor(p2, o, 64);
    p3 += __shfl_xor(p3, o, 64);
  }
  if (lane == 0){
    const float* ss = nsall + (size_t)s*3;
    const float* ds = nsall + (size_t)d*3;
    float r = p0;
    r += p1 * ss[0] * ds[0];
    r += p2 * ss[1] * ds[1];
    r += p3 * ss[2] * ds[2];
    out[wid] = r;
  }
}

extern "C" void kernel_launch(void* const* d_in, const int* in_sizes, int n_in,
                              void* d_out, int out_size, void* d_ws, size_t ws_size,
                              hipStream_t stream){
  const int*   edge_index = (const int*)d_in[0];
  const int*   eli        = (const int*)d_in[1];
  const float* ew         = (const float*)d_in[2];
  const float* emb        = (const float*)d_in[3];
  const float* gcw        = (const float*)d_in[4];
  const float* gcb        = (const float*)d_in[5];
  const float* biw        = (const float*)d_in[6];
  const float* bib        = (const float*)d_in[7];
  const int E   = in_sizes[2];
  const int Q   = in_sizes[1] / 2;
  const int N   = in_sizes[3] / DD;
  const int LYR = in_sizes[4] / (DD*DD);
  float* out = (float*)d_out;

  const int FS  = (LYR + 1) * DD;   // interleaved per-node feature stride (512 for LYR=3)
  const int FSU = FS / 2;

  char* base = (char*)d_ws;
  size_t off = 0;
  auto carve = [&](size_t bytes)->char*{
    char* r = base + off;
    off = align256(off + bytes);
    return r;
  };

  unsigned short* feat4  = (unsigned short*) carve((size_t)N*FS*sizeof(unsigned short));
  // msgh (layer loop) aliases csre (setup phase A temp) -- disjoint lifetimes
  size_t msgB_ = (size_t)N*DD*sizeof(unsigned short);
  size_t csreB_ = (size_t)E*sizeof(int2);
  unsigned short* msgh   = (unsigned short*) carve(msgB_ > csreB_ ? msgB_ : csreB_);
  int2*           csre   = (int2*)msgh;
  unsigned short* wb     = (unsigned short*) carve((size_t)LYR*DD*K2*sizeof(unsigned short));
  float*          nsall  = (float*)          carve((size_t)3*N*sizeof(float));
  int*            rowptr = (int*)            carve((size_t)(N+1)*sizeof(int));
  int*            deg    = (int*)            carve((size_t)N*sizeof(int));
  int*            bcnt   = (int*)            carve((size_t)NBMAX*sizeof(int));
  int*            bbase  = (int*)            carve((size_t)NBMAX*sizeof(int));
  int*            bcur   = (int*)            carve((size_t)NBMAX*sizeof(int));
  int*            psum   = (int*)            carve((size_t)NBMAX*sizeof(int));
  int*            pbase  = (int*)            carve((size_t)NBMAX*sizeof(int));
  int2*           csre2  = (int2*)           carve(((size_t)E + 7*(size_t)N + 8)*sizeof(int2));
  (void)n_in; (void)out_size; (void)ws_size;

  const int NB = (N + 127)/128;

  // setup: hist -> bucket scan -> raw fill -> rowdeg(+psum) -> pscan -> sort(+rowptr) -> pack+cvt
  hipMemsetAsync(bcnt, 0, (size_t)NB*sizeof(int), stream);
  bucket_hist_kernel<<<(E + 8191)/8192, 256, 0, stream>>>(edge_index, E, bcnt, NB);
  bucket_scan_kernel<<<1, 1024, 0, stream>>>(bcnt, bbase, bcur, NB);
  fill_binned_kernel<<<(E + 4095)/4096, 256, 0, stream>>>(edge_index, ew, E, bcur, csre, NB);
  bucket_rowdeg_kernel<<<NB, 256, 0, stream>>>(bbase, bcur, csre, deg, psum, N);
  pscan_kernel<<<1, 1024, 0, stream>>>(psum, pbase, rowptr + N, NB);
  sortbkt_kernel<<<NB, 256, 0, stream>>>(pbase, bbase, bcur, deg, csre, csre2, rowptr, N);
  {
    int total = LYR*DD*K2 + N*DD/2;
    pack_cvt_kernel<<<(total + 255)/256, 256, 0, stream>>>(
        gcw, biw, wb, LYR, emb, (unsigned int*)feat4, N*DD/2, FSU);
  }

  for (int l = 0; l < LYR; l++){
    int blocks = (int)(((size_t)N*64 + 255)/256);
    gather_kernel<<<blocks, 256, 0, stream>>>(rowptr, csre2, feat4 + (size_t)l*DD, FS,
                                              (unsigned int*)msgh, N);
    transform_mfma_kernel<<<(N + 127)/128, 256, 0, stream>>>(
        feat4 + (size_t)l*DD, msgh, FS, wb + (size_t)l*DD*K2,
        gcb + (size_t)l*DD, bib + (size_t)l*DD,
        feat4 + (size_t)(l+1)*DD, nsall + l, N);
  }
  {
    int blocks = (int)(((size_t)Q*64 + 255)/256);
    score_all_kernel<<<blocks, 256, 0, stream>>>(eli, Q, (const unsigned int*)feat4, FSU,
                                                 nsall, out);
  }
}

// Round 13
// 544.351 us; speedup vs baseline: 6.9316x; 1.0083x over previous
//
#include <hip/hip_runtime.h>

#define DD 128
#define K2 256     // concatenated K: [msg | ego*msg]
#define NBMAX 1024 // max bucket count (N/128)
#define COLMASK 0x01FFFFFF
#define SCAP 4096  // sortbkt LDS out-buffer capacity (entries)

typedef short short8 __attribute__((ext_vector_type(8)));
typedef float f32x4  __attribute__((ext_vector_type(4)));

static inline size_t align256(size_t x){ return (x + 255) & ~(size_t)255; }

__device__ __forceinline__ unsigned short f2bf(float x){
  unsigned int u = __builtin_bit_cast(unsigned int, x);
  u += 0x7fff + ((u >> 16) & 1);          // RNE fp32 -> bf16
  return (unsigned short)(u >> 16);
}
__device__ __forceinline__ float bf2f(unsigned short h){
  unsigned int u = ((unsigned int)h) << 16;
  return __builtin_bit_cast(float, u);
}

__device__ __forceinline__ short8 prod8(short8 mv, short8 ev){
  short8 r;
#pragma unroll
  for (int u = 0; u < 8; u++){
    float p = bf2f((unsigned short)mv[u]) * bf2f((unsigned short)ev[u]);
    r[u] = (short)f2bf(p);
  }
  return r;
}

// ---------------- bucket histogram: LDS hist -> few global atomics ----------------
__global__ __launch_bounds__(256) void bucket_hist_kernel(
    const int* __restrict__ ei, int E, int* __restrict__ bcnt, int NB){
  __shared__ int lh[NBMAX];
  int t = threadIdx.x;
  int base = blockIdx.x * 8192;
  for (int j = t; j < NB; j += 256) lh[j] = 0;
  __syncthreads();
#pragma unroll
  for (int i = 0; i < 32; i++){
    int e = base + i*256 + t;
    if (e < E) atomicAdd(&lh[ei[e] >> 7], 1);
  }
  __syncthreads();
  for (int j = t; j < NB; j += 256){
    int c = lh[j];
    if (c) atomicAdd(&bcnt[j], c);
  }
}

// ---------------- bucket scan: bbase = excl scan(bcnt); bcur = bbase ----------------
__global__ __launch_bounds__(1024) void bucket_scan_kernel(
    const int* __restrict__ bcnt, int* __restrict__ bbase, int* __restrict__ bcur, int NB){
  __shared__ int a[NBMAX], btmp[NBMAX];
  int t = threadIdx.x;
  a[t] = (t < NB) ? bcnt[t] : 0;
  __syncthreads();
  int* src = a; int* dst = btmp;
  for (int o = 1; o < 1024; o <<= 1){
    int val = src[t];
    if (t >= o) val += src[t - o];
    dst[t] = val;
    __syncthreads();
    int* tm = src; src = dst; dst = tm;
  }
  int excl = (t == 0) ? 0 : src[t-1];
  if (t < NB){ bbase[t] = excl; bcur[t] = excl; }
}

// ---------------- binned fill, phase A ----------------
__global__ __launch_bounds__(256) void fill_binned_kernel(
    const int* __restrict__ ei, const float* __restrict__ ew, int E,
    int* __restrict__ bcur, int2* __restrict__ csre, int NB){
  __shared__ int lhist[NBMAX];
  __shared__ int lbase[NBMAX];
  int t = threadIdx.x;
  int base = blockIdx.x * 4096;
  for (int j = t; j < NB; j += 256) lhist[j] = 0;
  __syncthreads();
  int rows[16];
#pragma unroll
  for (int i = 0; i < 16; i++){
    int e = base + i*256 + t;
    int r = (e < E) ? ei[e] : -1;
    rows[i] = r;
    if (r >= 0) atomicAdd(&lhist[r >> 7], 1);
  }
  __syncthreads();
  for (int j = t; j < NB; j += 256){
    int c = lhist[j];
    lbase[j] = c ? atomicAdd(&bcur[j], c) : 0;
    lhist[j] = 0;
  }
  __syncthreads();
#pragma unroll
  for (int i = 0; i < 16; i++){
    int e = base + i*256 + t;
    int r = rows[i];
    if (r >= 0){
      int b = r >> 7;
      int pos = lbase[b] + atomicAdd(&lhist[b], 1);
      int col = ei[E + e];
      float w = ew[e];
      csre[pos] = make_int2(((r & 127) << 25) | col, __float_as_int(w));
    }
  }
}

// ---------------- per-bucket row degrees + padded bucket sums ----------------
__global__ __launch_bounds__(256) void bucket_rowdeg_kernel(
    const int* __restrict__ bbase, const int* __restrict__ bcur,
    const int2* __restrict__ csre, int* __restrict__ deg, int* __restrict__ psum, int N){
  __shared__ int lc[128];
  __shared__ int red[128];
  int b = blockIdx.x, t = threadIdx.x;
  if (t < 128) lc[t] = 0;
  __syncthreads();
  int beg = bbase[b], end = bcur[b];
  for (int i = beg + t; i < end; i += 256)
    atomicAdd(&lc[((unsigned int)csre[i].x) >> 25], 1);
  __syncthreads();
  int gr = b*128 + t;
  int d = 0;
  if (t < 128 && gr < N){ d = lc[t]; deg[gr] = d; }
  if (t < 128) red[t] = (d + 7) & ~7;
  __syncthreads();
  for (int o = 64; o > 0; o >>= 1){
    if (t < o) red[t] += red[t+o];
    __syncthreads();
  }
  if (t == 0) psum[b] = red[0];
}

// ---------------- padded-bucket scan ----------------
__global__ __launch_bounds__(1024) void pscan_kernel(
    const int* __restrict__ psum, int* __restrict__ pbase, int* __restrict__ rowptrN, int NB){
  __shared__ int a[NBMAX], btmp[NBMAX];
  int t = threadIdx.x;
  a[t] = (t < NB) ? psum[t] : 0;
  __syncthreads();
  int* src = a; int* dst = btmp;
  for (int o = 1; o < 1024; o <<= 1){
    int val = src[t];
    if (t >= o) val += src[t - o];
    dst[t] = val;
    __syncthreads();
    int* tm = src; src = dst; dst = tm;
  }
  int excl = (t == 0) ? 0 : src[t-1];
  if (t < NB) pbase[t] = excl;
  if (t == NB-1) *rowptrN = excl + psum[t];
}

// ---------------- phase B: local rowptr derivation + LDS-staged rank/pad -> coalesced ------
// Pad entries are (col=0, w=0): w=0 contributes nothing, and ALL pad loads hit the
// same 256B line (node 0's row) -> L2-broadcast instead of random HBM fetch.
__global__ __launch_bounds__(256) void sortbkt_kernel(
    const int* __restrict__ pbase, const int* __restrict__ bbase, const int* __restrict__ bcur,
    const int* __restrict__ deg, const int2* __restrict__ csre, int2* __restrict__ csre2,
    int* __restrict__ rowptr, int N){
  __shared__ int2 obuf[SCAP];
  __shared__ int lrp[129];
  __shared__ int lcur[128];
  __shared__ int sa[128], sb[128];
  int b = blockIdx.x;
  int t = threadIdx.x;
  int r0 = b*128;
  int gr = r0 + t;
  int d = (t < 128 && gr < N) ? deg[gr] : 0;
  if (t < 128){ sa[t] = (d + 7) & ~7; lcur[t] = 0; }
  __syncthreads();
  int* s0 = sa; int* s1 = sb;
  for (int o = 1; o < 128; o <<= 1){
    if (t < 128){
      int v = s0[t];
      if (t >= o) v += s0[t - o];
      s1[t] = v;
    }
    __syncthreads();
    int* tm = s0; s0 = s1; s1 = tm;
  }
  int pb = pbase[b];
  if (t < 128){
    int excl = t ? s0[t-1] : 0;
    lrp[t] = pb + excl;
    if (gr < N) rowptr[gr] = pb + excl;
    if (t == 127) lrp[128] = pb + s0[127];
  }
  __syncthreads();

  int gb = lrp[0];
  int outLen = lrp[128] - gb;
  int beg = bbase[b], bend = bcur[b];
  const int2 pad = make_int2(0, 0);   // col 0, w 0 -> L2-hot no-op edge

  if (outLen <= SCAP){
    for (int i = beg + t; i < bend; i += 256){
      int2 e = csre[i];
      int rl = ((unsigned int)e.x) >> 25;
      int pos = lrp[rl] - gb + atomicAdd(&lcur[rl], 1);
      obuf[pos] = e;
    }
    if (t < 128 && gr < N){
      int pbg = lrp[t] - gb + d, pe = lrp[t+1] - gb;
      for (int i = pbg; i < pe; i++) obuf[i] = pad;
    }
    __syncthreads();
    for (int i = t; i < outLen; i += 256) csre2[gb + i] = obuf[i];
  } else {
    for (int i = beg + t; i < bend; i += 256){
      int2 e = csre[i];
      int rl = ((unsigned int)e.x) >> 25;
      int pos = lrp[rl] + atomicAdd(&lcur[rl], 1);
      csre2[pos] = e;
    }
    __syncthreads();
    if (t < 128 && gr < N){
      int pbeg = lrp[t] + lcur[t];
      int pend = lrp[t+1];
      for (int i = pbeg; i < pend; i++) csre2[i] = pad;
    }
  }
}

// ---------------- fused: weight pack + emb->bf16 stage0 (interleaved feat4) ----------------
__global__ void pack_cvt_kernel(const float* __restrict__ gcw, const float* __restrict__ biw,
                                unsigned short* __restrict__ wb, int LYR,
                                const float* __restrict__ emb, unsigned int* __restrict__ feat4u,
                                int n2, int fsU){
  int i = blockIdx.x*blockDim.x + threadIdx.x;
  int wtotal = LYR*DD*K2;
  if (i < wtotal){
    int l = i / (DD*K2);
    int r = i - l*(DD*K2);
    int n = r >> 8;
    int k = r & (K2-1);
    float v = (k < DD) ? gcw[(size_t)l*DD*DD + n*DD + k]
                       : biw[(size_t)l*DD*DD + n*DD + (k - DD)];
    wb[i] = f2bf(v);
    return;
  }
  int j = i - wtotal;
  if (j < n2){
    float2 v = *(const float2*)(emb + (size_t)j*2);
    int n = j >> 6, c = j & 63;
    feat4u[(size_t)n*fsU + c] = (unsigned int)f2bf(v.x) | ((unsigned int)f2bf(v.y) << 16);
  }
}

// ---------------- gather (tail-free, rows padded x8): 16-deep MLP ----------------
__global__ void gather_kernel(const int* __restrict__ rowptr, const int2* __restrict__ csre,
                              const unsigned short* __restrict__ feat, int fs,
                              unsigned int* __restrict__ msgh, int N){
  int wid = (int)(((size_t)blockIdx.x*blockDim.x + threadIdx.x) >> 6);
  int lane = threadIdx.x & 63;
  if (wid >= N) return;
  int beg = rowptr[wid], end = rowptr[wid+1];
  float ax = 0.f, ay = 0.f;
  int k = beg;
  for (; k + 16 <= end; k += 16){     // 16 independent row-gathers in flight
    int2 e[16]; unsigned int v[16];
#pragma unroll
    for (int u = 0; u < 16; u++) e[u] = csre[k+u];
#pragma unroll
    for (int u = 0; u < 16; u++)
      v[u] = *(const unsigned int*)(feat + (size_t)(e[u].x & COLMASK)*fs + lane*2);
#pragma unroll
    for (int u = 0; u < 16; u++){
      float w = __int_as_float(e[u].y);
      ax = fmaf(w, bf2f((unsigned short)v[u]), ax);
      ay = fmaf(w, bf2f((unsigned short)(v[u]>>16)), ay);
    }
  }
  for (; k < end; k += 8){            // at most one trailing 8-batch (rows padded x8)
    int2 e[8]; unsigned int v[8];
#pragma unroll
    for (int u = 0; u < 8; u++) e[u] = csre[k+u];
#pragma unroll
    for (int u = 0; u < 8; u++)
      v[u] = *(const unsigned int*)(feat + (size_t)(e[u].x & COLMASK)*fs + lane*2);
#pragma unroll
    for (int u = 0; u < 8; u++){
      float w = __int_as_float(e[u].y);
      ax = fmaf(w, bf2f((unsigned short)v[u]), ax);
      ay = fmaf(w, bf2f((unsigned short)(v[u]>>16)), ay);
    }
  }
  msgh[(size_t)wid*(DD/2) + lane] = (unsigned int)f2bf(ax) | ((unsigned int)f2bf(ay) << 16);
}

// ---------------- transform (bf16 MFMA, K=256), LDS-free, strided feature rows ----------
__global__ __launch_bounds__(256) void transform_mfma_kernel(
    const unsigned short* __restrict__ ego_in, const unsigned short* __restrict__ msgh,
    int fs, const unsigned short* __restrict__ wb, const float* __restrict__ gcb,
    const float* __restrict__ bib, unsigned short* __restrict__ ego_out,
    float* __restrict__ nscale, int N){   // nscale: stride-3 base for this layer
  int t = threadIdx.x;
  int wave = t >> 6, lane = t & 63;
  int m = lane & 15, q = lane >> 4;
  int wr0 = blockIdx.x * 128 + wave * 32;

  float bias[8];
#pragma unroll
  for (int ct = 0; ct < 8; ct++) bias[ct] = gcb[ct*16 + m] + bib[ct*16 + m];

  int row0 = wr0 + m, row1 = wr0 + 16 + m;
  int cr0 = row0 < N ? row0 : N-1;
  int cr1 = row1 < N ? row1 : N-1;
  const unsigned short* mrow0 = msgh   + (size_t)cr0*DD;
  const unsigned short* mrow1 = msgh   + (size_t)cr1*DD;
  const unsigned short* erow0 = ego_in + (size_t)cr0*fs;
  const unsigned short* erow1 = ego_in + (size_t)cr1*fs;
  const unsigned short* wrow  = wb + (size_t)m*K2;

  f32x4 acc[8][2];
#pragma unroll
  for (int ct = 0; ct < 8; ct++){ acc[ct][0] = (f32x4)0.f; acc[ct][1] = (f32x4)0.f; }

#pragma unroll
  for (int cc = 0; cc < 4; cc++){
    int c = cc*32 + q*8;
    short8 m0 = *(const short8*)(mrow0 + c);
    short8 m1 = *(const short8*)(mrow1 + c);
    short8 e0 = *(const short8*)(erow0 + c);
    short8 e1 = *(const short8*)(erow1 + c);
    short8 p0 = prod8(m0, e0);
    short8 p1 = prod8(m1, e1);
#pragma unroll
    for (int ct = 0; ct < 8; ct++){
      short8 bm = *(const short8*)(wrow + (size_t)ct*16*K2 + c);
      short8 bp = *(const short8*)(wrow + (size_t)ct*16*K2 + DD + c);
      acc[ct][0] = __builtin_amdgcn_mfma_f32_16x16x32_bf16(m0, bm, acc[ct][0], 0, 0, 0);
      acc[ct][1] = __builtin_amdgcn_mfma_f32_16x16x32_bf16(m1, bm, acc[ct][1], 0, 0, 0);
      acc[ct][0] = __builtin_amdgcn_mfma_f32_16x16x32_bf16(p0, bp, acc[ct][0], 0, 0, 0);
      acc[ct][1] = __builtin_amdgcn_mfma_f32_16x16x32_bf16(p1, bp, acc[ct][1], 0, 0, 0);
    }
  }

#pragma unroll
  for (int rt = 0; rt < 2; rt++){
#pragma unroll
    for (int reg = 0; reg < 4; reg++){
      int gr = wr0 + rt*16 + q*4 + reg;
      float rs = 0.f;
#pragma unroll
      for (int ct = 0; ct < 8; ct++){
        float x = acc[ct][rt][reg] + bias[ct];
        x = (x > 0.f) ? x : 0.2f*x;
        rs += x*x;
        if (gr < N) ego_out[(size_t)gr*fs + ct*16 + m] = f2bf(x);
      }
#pragma unroll
      for (int o = 1; o < 16; o <<= 1) rs += __shfl_xor(rs, o, 16);
      if (m == 0 && gr < N)
        nscale[(size_t)gr*3] = 1.0f / fmaxf(sqrtf(rs), 1e-12f);
    }
  }
}

// ---------------- score: single pass, interleaved 4-stage rows + interleaved scales --------
__global__ void score_all_kernel(const int* __restrict__ eli, int Q,
                                 const unsigned int* __restrict__ feat4u, int fsU,
                                 const float* __restrict__ nsall,  // [n][3]
                                 float* __restrict__ out){
  int wid = (int)(((size_t)blockIdx.x*blockDim.x + threadIdx.x) >> 6);
  int lane = threadIdx.x & 63;
  if (wid >= Q) return;
  int s = eli[wid];
  int d = eli[Q + wid];
  const unsigned int* sr = feat4u + (size_t)s*fsU + lane;
  const unsigned int* dr = feat4u + (size_t)d*fsU + lane;
  unsigned int a0 = sr[0],   b0 = dr[0];
  unsigned int a1 = sr[64],  b1 = dr[64];
  unsigned int a2 = sr[128], b2 = dr[128];
  unsigned int a3 = sr[192], b3 = dr[192];
  float p0 = bf2f((unsigned short)a0)*bf2f((unsigned short)b0)
           + bf2f((unsigned short)(a0>>16))*bf2f((unsigned short)(b0>>16));
  float p1 = bf2f((unsigned short)a1)*bf2f((unsigned short)b1)
           + bf2f((unsigned short)(a1>>16))*bf2f((unsigned short)(b1>>16));
  float p2 = bf2f((unsigned short)a2)*bf2f((unsigned short)b2)
           + bf2f((unsigned short)(a2>>16))*bf2f((unsigned short)(b2>>16));
  float p3 = bf2f((unsigned short)a3)*bf2f((unsigned short)b3)
           + bf2f((unsigned short)(a3>>16))*bf2f((unsigned short)(b3>>16));
  for (int o = 32; o > 0; o >>= 1){
    p0 += __shfl_xor(p0, o, 64);
    p1 += __shfl_xor(p1, o, 64);
    p2 += __shfl_xor(p2, o, 64);
    p3 += __shfl_xor(p3, o, 64);
  }
  if (lane == 0){
    const float* ss = nsall + (size_t)s*3;
    const float* ds = nsall + (size_t)d*3;
    float r = p0;
    r += p1 * ss[0] * ds[0];
    r += p2 * ss[1] * ds[1];
    r += p3 * ss[2] * ds[2];
    out[wid] = r;
  }
}

extern "C" void kernel_launch(void* const* d_in, const int* in_sizes, int n_in,
                              void* d_out, int out_size, void* d_ws, size_t ws_size,
                              hipStream_t stream){
  const int*   edge_index = (const int*)d_in[0];
  const int*   eli        = (const int*)d_in[1];
  const float* ew         = (const float*)d_in[2];
  const float* emb        = (const float*)d_in[3];
  const float* gcw        = (const float*)d_in[4];
  const float* gcb        = (const float*)d_in[5];
  const float* biw        = (const float*)d_in[6];
  const float* bib        = (const float*)d_in[7];
  const int E   = in_sizes[2];
  const int Q   = in_sizes[1] / 2;
  const int N   = in_sizes[3] / DD;
  const int LYR = in_sizes[4] / (DD*DD);
  float* out = (float*)d_out;

  const int FS  = (LYR + 1) * DD;   // interleaved per-node feature stride (512 for LYR=3)
  const int FSU = FS / 2;

  char* base = (char*)d_ws;
  size_t off = 0;
  auto carve = [&](size_t bytes)->char*{
    char* r = base + off;
    off = align256(off + bytes);
    return r;
  };

  unsigned short* feat4  = (unsigned short*) carve((size_t)N*FS*sizeof(unsigned short));
  // msgh (layer loop) aliases csre (setup phase A temp) -- disjoint lifetimes
  size_t msgB_ = (size_t)N*DD*sizeof(unsigned short);
  size_t csreB_ = (size_t)E*sizeof(int2);
  unsigned short* msgh   = (unsigned short*) carve(msgB_ > csreB_ ? msgB_ : csreB_);
  int2*           csre   = (int2*)msgh;
  unsigned short* wb     = (unsigned short*) carve((size_t)LYR*DD*K2*sizeof(unsigned short));
  float*          nsall  = (float*)          carve((size_t)3*N*sizeof(float));
  int*            rowptr = (int*)            carve((size_t)(N+1)*sizeof(int));
  int*            deg    = (int*)            carve((size_t)N*sizeof(int));
  int*            bcnt   = (int*)            carve((size_t)NBMAX*sizeof(int));
  int*            bbase  = (int*)            carve((size_t)NBMAX*sizeof(int));
  int*            bcur   = (int*)            carve((size_t)NBMAX*sizeof(int));
  int*            psum   = (int*)            carve((size_t)NBMAX*sizeof(int));
  int*            pbase  = (int*)            carve((size_t)NBMAX*sizeof(int));
  int2*           csre2  = (int2*)           carve(((size_t)E + 7*(size_t)N + 8)*sizeof(int2));
  (void)n_in; (void)out_size; (void)ws_size;

  const int NB = (N + 127)/128;

  // setup: hist -> bucket scan -> raw fill -> rowdeg(+psum) -> pscan -> sort(+rowptr) -> pack+cvt
  hipMemsetAsync(bcnt, 0, (size_t)NB*sizeof(int), stream);
  bucket_hist_kernel<<<(E + 8191)/8192, 256, 0, stream>>>(edge_index, E, bcnt, NB);
  bucket_scan_kernel<<<1, 1024, 0, stream>>>(bcnt, bbase, bcur, NB);
  fill_binned_kernel<<<(E + 4095)/4096, 256, 0, stream>>>(edge_index, ew, E, bcur, csre, NB);
  bucket_rowdeg_kernel<<<NB, 256, 0, stream>>>(bbase, bcur, csre, deg, psum, N);
  pscan_kernel<<<1, 1024, 0, stream>>>(psum, pbase, rowptr + N, NB);
  sortbkt_kernel<<<NB, 256, 0, stream>>>(pbase, bbase, bcur, deg, csre, csre2, rowptr, N);
  {
    int total = LYR*DD*K2 + N*DD/2;
    pack_cvt_kernel<<<(total + 255)/256, 256, 0, stream>>>(
        gcw, biw, wb, LYR, emb, (unsigned int*)feat4, N*DD/2, FSU);
  }

  for (int l = 0; l < LYR; l++){
    int blocks = (int)(((size_t)N*64 + 255)/256);
    gather_kernel<<<blocks, 256, 0, stream>>>(rowptr, csre2, feat4 + (size_t)l*DD, FS,
                                              (unsigned int*)msgh, N);
    transform_mfma_kernel<<<(N + 127)/128, 256, 0, stream>>>(
        feat4 + (size_t)l*DD, msgh, FS, wb + (size_t)l*DD*K2,
        gcb + (size_t)l*DD, bib + (size_t)l*DD,
        feat4 + (size_t)(l+1)*DD, nsall + l, N);
  }
  {
    int blocks = (int)(((size_t)Q*64 + 255)/256);
    score_all_kernel<<<blocks, 256, 0, stream>>>(eli, Q, (const unsigned int*)feat4, FSU,
                                                 nsall, out);
  }
}